// Round 19
// baseline (99.061 us; speedup 1.0000x reference)
//
#include <hip/hip_runtime.h>

// Problem constants: B=16, MAX_LEN=100, LOC_MAX=20000, EMB=256, D_DELTA=2
#define NB 16
#define MLEN 100
#define EMBD 256
#define LMAX 20000
#define LTILE 64            // l's per block
#define NLT 313             // ceil(20000/64); last tile: 32 valid l's (masked)
#define NKC 4               // K chunks of 32 m's (100 zero-padded to 128 in B)
#define PREP_TASKS (NB * NKC * 16 * 64)   // 65536: (b,kc,etg,lane)

typedef __attribute__((ext_vector_type(4))) float f32x4;
typedef _Float16 f16x8 __attribute__((ext_vector_type(8)));
typedef const __attribute__((address_space(1))) unsigned int* as1_u32p;
typedef __attribute__((address_space(3))) unsigned int* as3_u32p;

__device__ __forceinline__ unsigned short f2h(float x) {
    union { _Float16 f; unsigned short u; } a; a.f = (_Float16)x; return a.u;
}

// ---------------- Kernel 1: pack vwA = vw[m]*attn[b][m][e] into single-f16 MFMA B-fragments ----------------
// frag f = (b*NKC+kc)*16 + etg ; lane: e = etg*16 + (lane&15), k = (lane>>4)*8 + j, m = kc*32 + k
// m >= MLEN -> exact zero
__global__ __launch_bounds__(256)
void prep2_kernel(const float* __restrict__ attn, const float* __restrict__ vw,
                  unsigned short* __restrict__ Bf) {
    const int gid  = blockIdx.x * 256 + threadIdx.x;   // < 65536
    const int lane = gid & 63;
    const int f    = gid >> 6;
    const int etg  = f & 15;
    const int kcb  = f >> 4;
    const int kc   = kcb & 3;
    const int b    = kcb >> 2;
    const int e    = etg * 16 + (lane & 15);
    const int m0   = kc * 32 + (lane >> 4) * 8;
    unsigned h[8];
    #pragma unroll
    for (int j = 0; j < 8; ++j) {
        const int m = m0 + j;
        float x = 0.f;
        if (m < MLEN) x = vw[m] * attn[((size_t)b * MLEN + m) * EMBD + e];
        h[j] = f2h(x);
    }
    uint4 hi = make_uint4(h[0]|(h[1]<<16), h[2]|(h[3]<<16), h[4]|(h[5]<<16), h[6]|(h[7]<<16));
    reinterpret_cast<uint4*>(Bf)[gid] = hi;
}

// ---------------- Kernel 2: fire-and-forget global_load_lds pipeline, counted vmcnt ----------------
// Block: (b, 64 l's), 4 waves; wave w owns e-range [w*64,+64). K = 100 m's in 4 chunks of 32.
// Per chunk: 16 SD-instrs (raw f32 rows, 2 rows/instr) + 16 B-instrs, split 8/wave, all
// global_load_lds (zero VGPR). 2 chunks in flight always. Loop: vmcnt(8) [counted, never 0
// until tail] -> s_barrier -> ds_read B frags + per-lt {8x ds_read_b64 SD, pair-sum, f16 pack,
// 4 MFMA} -> s_barrier -> issue chunk kc+2 into freed buffer.
__global__ __launch_bounds__(256, 2)
void main_kernel(const unsigned short* __restrict__ Bf,
                 const float* __restrict__ sdelta, const float* __restrict__ embt,
                 float* __restrict__ out) {
    __shared__ __align__(16) char SD[2][32 * 512];    // raw sdelta chunk: [32 m][64 l x f32x2]
    __shared__ __align__(16) char BL[2][16 * 1024];   // B frags: [etg][64 lanes x 16B]
    __shared__ float red[256];                        // total 66560 B -> 2 blocks/CU

    const int b    = blockIdx.x;
    const int lt0  = blockIdx.y;
    const int l0   = lt0 * LTILE;
    const int w    = threadIdx.x >> 6;
    const int lane = threadIdx.x & 63;
    const int llo  = lane & 15;
    const int lhi  = lane >> 4;

    f32x4 acc[4][4];
    #pragma unroll
    for (int lt = 0; lt < 4; ++lt)
        #pragma unroll
        for (int et = 0; et < 4; ++et)
            acc[lt][et] = (f32x4){0.f, 0.f, 0.f, 0.f};

    // per-lane SD source: lane covers 2 l's (16B) of a row-pair; clamp for edge tile (aligned: even*8B)
    const int rhalf = lane >> 5;                  // which row of the pair
    const int lp    = lane & 31;                  // l-pair index within row
    const int lcl   = min(l0 + 2 * lp, LMAX - 2);

    auto stageChunk = [&](int kc) {
        const int q = kc & 1;
        #pragma unroll
        for (int jj = 0; jj < 4; ++jj) {          // SD: instr j covers rows {2j, 2j+1}
            const int j = w + 4 * jj;
            const int m = kc * 32 + 2 * j + rhalf;
            const float* src = sdelta + ((size_t)(b * MLEN + min(m, MLEN - 1)) * LMAX + lcl) * 2;
            char* dst = &SD[q][j * 1024];         // uniform; HW adds lane*16
            __builtin_amdgcn_global_load_lds((as1_u32p)(const void*)src,
                                             (as3_u32p)(void*)dst, 16, 0, 0);
        }
        #pragma unroll
        for (int jj = 0; jj < 4; ++jj) {          // B: instr = one fragment (1 KB)
            const int floc = w + 4 * jj;
            const unsigned short* src = Bf + (((size_t)(b * NKC + kc) * 16 + floc) * 64 + lane) * 8;
            char* dst = &BL[q][floc * 1024];
            __builtin_amdgcn_global_load_lds((as1_u32p)(const void*)src,
                                             (as3_u32p)(void*)dst, 16, 0, 0);
        }
    };

    stageChunk(0);
    stageChunk(1);

    #pragma unroll
    for (int kc = 0; kc < NKC; ++kc) {
        const int q = kc & 1;
        __builtin_amdgcn_sched_barrier(0);
        if (kc < NKC - 1) asm volatile("s_waitcnt vmcnt(8)" ::: "memory");   // counted: next chunk stays in flight
        else              asm volatile("s_waitcnt vmcnt(0)" ::: "memory");   // tail only
        __builtin_amdgcn_sched_barrier(0);
        __builtin_amdgcn_s_barrier();             // all waves' chunk-kc loads visible
        __builtin_amdgcn_sched_barrier(0);

        // B fragments for this wave (LDS -> regs)
        f16x8 bb[4];
        #pragma unroll
        for (int et = 0; et < 4; ++et)
            bb[et] = *reinterpret_cast<const f16x8*>(&BL[q][(w * 4 + et) * 1024 + lane * 16]);

        // per-lt: read raw SD pairs, mask+sum+pack to f16, 4 MFMAs
        #pragma unroll
        for (int lt = 0; lt < 4; ++lt) {
            const int base = (lt * 16 + llo) * 8;
            float2 vv[8];
            #pragma unroll
            for (int j = 0; j < 8; ++j)
                vv[j] = *reinterpret_cast<const float2*>(&SD[q][(lhi * 8 + j) * 512 + base]);
            unsigned u[4];
            #pragma unroll
            for (int jp = 0; jp < 4; ++jp) {
                const int mg = kc * 32 + lhi * 8 + 2 * jp;
                const float s0 = (mg     < MLEN) ? (vv[2 * jp].x + vv[2 * jp].y) : 0.f;
                const float s1 = (mg + 1 < MLEN) ? (vv[2 * jp + 1].x + vv[2 * jp + 1].y) : 0.f;
                u[jp] = (unsigned)f2h(s0) | ((unsigned)f2h(s1) << 16);
            }
            union { uint4 ui; f16x8 v; } ac;
            ac.ui = make_uint4(u[0], u[1], u[2], u[3]);
            #pragma unroll
            for (int et = 0; et < 4; ++et)
                acc[lt][et] = __builtin_amdgcn_mfma_f32_16x16x32_f16(ac.v, bb[et], acc[lt][et], 0, 0, 0);
        }

        __builtin_amdgcn_sched_barrier(0);
        __builtin_amdgcn_s_barrier();             // all waves done READING buf q
        __builtin_amdgcn_sched_barrier(0);
        if (kc + 2 < NKC) stageChunk(kc + 2);     // safe overwrite; ~2 phases of latency cover
        __builtin_amdgcn_sched_barrier(0);
    }

    // ---------------- epilogue: p[l] = sum_e G[l,e] * E[1+l, e] ----------------
    // C/D layout: col = lane&15 (e), row = (lane>>4)*4 + i (l)  [verified r1-r18]
    float p[4][4];
    #pragma unroll
    for (int lt = 0; lt < 4; ++lt) {
        #pragma unroll
        for (int i = 0; i < 4; ++i) {
            const int l  = l0 + lt * 16 + lhi * 4 + i;
            const int lc = (l < LMAX) ? l : (LMAX - 1);
            const float* Er = embt + (size_t)(1 + lc) * EMBD + w * 64 + llo;
            float s = acc[lt][0][i] * Er[0];
            s += acc[lt][1][i] * Er[16];
            s += acc[lt][2][i] * Er[32];
            s += acc[lt][3][i] * Er[48];
            p[lt][i] = s;
        }
    }
    #pragma unroll
    for (int lt = 0; lt < 4; ++lt)
        #pragma unroll
        for (int i = 0; i < 4; ++i) {
            float x = p[lt][i];
            x += __shfl_xor(x, 1);
            x += __shfl_xor(x, 2);
            x += __shfl_xor(x, 4);
            x += __shfl_xor(x, 8);
            p[lt][i] = x;
        }
    if (llo == 0) {
        #pragma unroll
        for (int lt = 0; lt < 4; ++lt)
            *reinterpret_cast<float4*>(&red[w * 64 + lt * 16 + lhi * 4]) =
                make_float4(p[lt][0], p[lt][1], p[lt][2], p[lt][3]);
    }
    __syncthreads();
    if (threadIdx.x < 64) {
        const int t = threadIdx.x;
        const int l = l0 + t;
        if (l < LMAX) {
            out[(size_t)b * LMAX + l] = red[t] + red[64 + t] + red[128 + t] + red[192 + t];
        }
    }
}

// ---------------- Fallback (ws too small): straightforward f32 compute ----------------
__global__ __launch_bounds__(256)
void fallback_kernel(const float* __restrict__ attn, const float* __restrict__ sdelta,
                     const float* __restrict__ embt, const float* __restrict__ vw,
                     float* __restrict__ out) {
    const int idx = blockIdx.x * 256 + threadIdx.x;
    if (idx >= NB * LMAX) return;
    const int b = idx / LMAX;
    const int l = idx % LMAX;
    float s = 0.f;
    for (int m = 0; m < MLEN; ++m) {
        const float* ar = attn + ((size_t)b * MLEN + m) * EMBD;
        const float* er = embt + (size_t)(l + 1) * EMBD;
        float dot = 0.f;
        for (int e = 0; e < EMBD; ++e) dot += ar[e] * er[e];
        const size_t so = (((size_t)b * MLEN + m) * LMAX + l) * 2;
        s += dot * vw[m] * (sdelta[so] + sdelta[so + 1]);
    }
    out[idx] = s;
}

extern "C" void kernel_launch(void* const* d_in, const int* in_sizes, int n_in,
                              void* d_out, int out_size, void* d_ws, size_t ws_size,
                              hipStream_t stream) {
    const float* attn   = (const float*)d_in[0];  // [16][100][256] f32
    const float* sdelta = (const float*)d_in[1];  // [16][100][20000][2] f32
    // d_in[2] = traj_len — unused by the reference computation
    const float* embt   = (const float*)d_in[3];  // [20001][256] f32
    const float* vw     = (const float*)d_in[4];  // [1][100] f32
    float* out = (float*)d_out;                   // [16][20000] f32

    const size_t fragShorts = (size_t)PREP_TASKS * 8;                // 524288 u16
    const size_t needed     = fragShorts * sizeof(unsigned short);   // 1 MB

    if (ws_size >= needed) {
        unsigned short* Bf = (unsigned short*)d_ws;
        prep2_kernel<<<PREP_TASKS / 256, 256, 0, stream>>>(attn, vw, Bf);
        main_kernel<<<dim3(NB, NLT), 256, 0, stream>>>(Bf, sdelta, embt, out);
    } else {
        fallback_kernel<<<(NB * LMAX + 255) / 256, 256, 0, stream>>>(attn, sdelta, embt, vw, out);
    }
}

// Round 20
// 78.210 us; speedup vs baseline: 1.2666x; 1.2666x over previous
//
#include <hip/hip_runtime.h>

// Problem constants: B=16, MAX_LEN=100, LOC_MAX=20000, EMB=256, D_DELTA=2
#define NB 16
#define MLEN 100
#define EMBD 256
#define LMAX 20000
#define LTILE 128           // l's per block (lane owns an l-pair)
#define NLT 157             // ceil(20000/128)
#define NKC 4               // K chunks of 32 m's (100 zero-padded to 128 in B)
#define FSTRIDE 520         // u16 per lsub sub-tile: 512 data + 8 pad (1040 B, 16B-aligned)
#define PREP_TASKS (NB * NKC * 16 * 64)   // 65536: (b,kc,etg,lane)

typedef __attribute__((ext_vector_type(4))) float f32x4;
typedef _Float16 f16x8 __attribute__((ext_vector_type(8)));

__device__ __forceinline__ unsigned short f2h(float x) {
    union { _Float16 f; unsigned short u; } a; a.f = (_Float16)x; return a.u;
}

// ---------------- Kernel 1: pack vwA = vw[m]*attn[b][m][e] into single-f16 MFMA B-fragments ----------------
// frag f = (b*NKC+kc)*16 + etg ; lane: e = etg*16 + (lane&15), k = (lane>>4)*8 + j, m = kc*32 + k
// m >= MLEN -> exact zero
__global__ __launch_bounds__(256)
void prep2_kernel(const float* __restrict__ attn, const float* __restrict__ vw,
                  unsigned short* __restrict__ Bf) {
    const int gid  = blockIdx.x * 256 + threadIdx.x;   // < 65536
    const int lane = gid & 63;
    const int f    = gid >> 6;
    const int etg  = f & 15;
    const int kcb  = f >> 4;
    const int kc   = kcb & 3;
    const int b    = kcb >> 2;
    const int e    = etg * 16 + (lane & 15);
    const int m0   = kc * 32 + (lane >> 4) * 8;
    unsigned h[8];
    #pragma unroll
    for (int j = 0; j < 8; ++j) {
        const int m = m0 + j;
        float x = 0.f;
        if (m < MLEN) x = vw[m] * attn[((size_t)b * MLEN + m) * EMBD + e];
        h[j] = f2h(x);
    }
    uint4 hi = make_uint4(h[0]|(h[1]<<16), h[2]|(h[3]<<16), h[4]|(h[5]<<16), h[6]|(h[7]<<16));
    reinterpret_cast<uint4*>(Bf)[gid] = hi;
}

// ---------------- Kernel 2: single-pass f16 GEMM, LTILE=128, 2-phase-deep A prefetch ----------------
// R18 structure (verified 72.4 us) + loadB hoisted pre-barrier + setprio around MFMA cluster.
// Block: (b, 128 l's), 4 waves; wave w owns e-range [w*64,+64). K = 100 m's in 4 chunks of 32.
// Pipeline (per kc): writeA(kc) [consumes slot q; conversion covered by prefetch distance] ->
// issueA(kc+2) into freed slot q -> loadB(kc+1) [global, pre-barrier] -> raw s_barrier
// (lgkmcnt only, no vmcnt drain) -> setprio(1) 32 MFMA setprio(0).
__global__ __launch_bounds__(256, 2)
void main_kernel(const unsigned short* __restrict__ Bf,
                 const float* __restrict__ sdelta, const float* __restrict__ embt,
                 float* __restrict__ out) {
    __shared__ __align__(16) unsigned short AhL[2][8 * FSTRIDE];  // 2 x 8320 B
    __shared__ float red[512];                                    // 2048 B (total 18688 B)

    const int b    = blockIdx.x;
    const int lt0  = blockIdx.y;
    const int l0   = lt0 * LTILE;
    const int w    = threadIdx.x >> 6;
    const int lane = threadIdx.x & 63;
    const int llo  = lane & 15;
    const int lhi  = lane >> 4;

    f32x4 acc[8][4];
    #pragma unroll
    for (int lt = 0; lt < 8; ++lt)
        #pragma unroll
        for (int et = 0; et < 4; ++et)
            acc[lt][et] = (f32x4){0.f, 0.f, 0.f, 0.f};

    // per-lane global source: 2 consecutive l's (one f32x4), clamped for the edge tile
    const int lcl = min(l0 + 2 * lane, LMAX - 2);

    f32x4 vA[2][8];
    // wave w loads rows r32 = w*8 + jj (8 consecutive rows), each lane its l-pair (16B coalesced)
    auto issueA = [&](int kc) {
        const int q = kc & 1;
        #pragma unroll
        for (int jj = 0; jj < 8; ++jj) {
            const int m  = kc * 32 + w * 8 + jj;
            const int mc = (m < MLEN) ? m : (MLEN - 1);
            vA[q][jj] = *reinterpret_cast<const f32x4*>(
                            sdelta + ((size_t)(b * MLEN + mc) * LMAX + lcl) * 2);
        }
    };
    // pair-sum -> f16; lane's 8 j-elements contiguous -> 2 x ds_write_b128 (l even, l odd)
    auto writeA = [&](int kc) {
        const int q   = kc & 1;
        const int lt  = lane >> 3;          // lsub of this lane's l-pair
        const int lo0 = (2 * lane) & 15;    // row (l) within 16-tile, even
        unsigned h0[8], h1[8];
        #pragma unroll
        for (int jj = 0; jj < 8; ++jj) {
            const int m = kc * 32 + w * 8 + jj;
            const float msk = (m < MLEN) ? 1.f : 0.f;
            const f32x4 v = vA[q][jj];
            h0[jj] = f2h((v[0] + v[1]) * msk);
            h1[jj] = f2h((v[2] + v[3]) * msk);
        }
        const int i0 = lt * FSTRIDE + (lo0 | (w << 4)) * 8;   // kg == w
        *reinterpret_cast<uint4*>(&AhL[q][i0]) =
            make_uint4(h0[0]|(h0[1]<<16), h0[2]|(h0[3]<<16), h0[4]|(h0[5]<<16), h0[6]|(h0[7]<<16));
        *reinterpret_cast<uint4*>(&AhL[q][i0 + 8]) =
            make_uint4(h1[0]|(h1[1]<<16), h1[2]|(h1[3]<<16), h1[4]|(h1[5]<<16), h1[6]|(h1[7]<<16));
    };
    auto loadB = [&](int kc, f16x8* dst) {
        #pragma unroll
        for (int et = 0; et < 4; ++et) {
            const size_t bo = (((size_t)(b * NKC + kc) * 16 + (w * 4 + et)) * 64 + lane) * 8;
            dst[et] = *reinterpret_cast<const f16x8*>(Bf + bo);
        }
    };

    f16x8 Bc[4], Bn[4];
    issueA(0);                                   // slot 0 in flight
    issueA(1);                                   // slot 1 in flight
    loadB(0, Bc);
    #pragma unroll
    for (int kc = 0; kc < NKC; ++kc) {
        const int q = kc & 1;
        writeA(kc);                              // counted wait on slot q only (2-phase-old loads)
        if (kc + 2 < NKC) issueA(kc + 2);        // refill freed slot q: ~2 phases of latency cover
        if (kc + 1 < NKC) loadB(kc + 1, Bn);     // global B prefetch, pre-barrier; wait lands post-MFMA
        __builtin_amdgcn_sched_barrier(0);
        asm volatile("s_waitcnt lgkmcnt(0)" ::: "memory");
        __builtin_amdgcn_sched_barrier(0);
        __builtin_amdgcn_s_barrier();            // raw barrier: no vmcnt drain
        __builtin_amdgcn_sched_barrier(0);

        __builtin_amdgcn_s_setprio(1);
        #pragma unroll
        for (int lt = 0; lt < 8; ++lt) {
            const f16x8 ah = *reinterpret_cast<const f16x8*>(&AhL[q][lt * FSTRIDE + lane * 8]);
            #pragma unroll
            for (int et = 0; et < 4; ++et)
                acc[lt][et] = __builtin_amdgcn_mfma_f32_16x16x32_f16(ah, Bc[et], acc[lt][et], 0, 0, 0);
        }
        __builtin_amdgcn_s_setprio(0);
        if (kc + 1 < NKC) { Bc[0] = Bn[0]; Bc[1] = Bn[1]; Bc[2] = Bn[2]; Bc[3] = Bn[3]; }
        // no second barrier: buf q next written at kc+2, ordered by kc+1's barrier (r13/r16-verified)
    }

    // ---------------- epilogue: p[l] = sum_e G[l,e] * E[1+l, e] ----------------
    // C/D layout: col = lane&15 (e), row = (lane>>4)*4 + i (l)  [verified r1-r19]
    float p[8][4];
    #pragma unroll
    for (int lt = 0; lt < 8; ++lt) {
        #pragma unroll
        for (int i = 0; i < 4; ++i) {
            const int l  = l0 + lt * 16 + lhi * 4 + i;
            const int lc = (l < LMAX) ? l : (LMAX - 1);
            const float* Er = embt + (size_t)(1 + lc) * EMBD + w * 64 + llo;
            float s = acc[lt][0][i] * Er[0];
            s += acc[lt][1][i] * Er[16];
            s += acc[lt][2][i] * Er[32];
            s += acc[lt][3][i] * Er[48];
            p[lt][i] = s;
        }
    }
    #pragma unroll
    for (int lt = 0; lt < 8; ++lt)
        #pragma unroll
        for (int i = 0; i < 4; ++i) {
            float x = p[lt][i];
            x += __shfl_xor(x, 1);
            x += __shfl_xor(x, 2);
            x += __shfl_xor(x, 4);
            x += __shfl_xor(x, 8);
            p[lt][i] = x;
        }
    if (llo == 0) {
        #pragma unroll
        for (int lt = 0; lt < 8; ++lt)
            *reinterpret_cast<float4*>(&red[w * 128 + lt * 16 + lhi * 4]) =
                make_float4(p[lt][0], p[lt][1], p[lt][2], p[lt][3]);
    }
    __syncthreads();
    if (threadIdx.x < 128) {
        const int t = threadIdx.x;
        const int l = l0 + t;
        if (l < LMAX) {
            out[(size_t)b * LMAX + l] = red[t] + red[128 + t] + red[256 + t] + red[384 + t];
        }
    }
}

// ---------------- Fallback (ws too small): straightforward f32 compute ----------------
__global__ __launch_bounds__(256)
void fallback_kernel(const float* __restrict__ attn, const float* __restrict__ sdelta,
                     const float* __restrict__ embt, const float* __restrict__ vw,
                     float* __restrict__ out) {
    const int idx = blockIdx.x * 256 + threadIdx.x;
    if (idx >= NB * LMAX) return;
    const int b = idx / LMAX;
    const int l = idx % LMAX;
    float s = 0.f;
    for (int m = 0; m < MLEN; ++m) {
        const float* ar = attn + ((size_t)b * MLEN + m) * EMBD;
        const float* er = embt + (size_t)(l + 1) * EMBD;
        float dot = 0.f;
        for (int e = 0; e < EMBD; ++e) dot += ar[e] * er[e];
        const size_t so = (((size_t)b * MLEN + m) * LMAX + l) * 2;
        s += dot * vw[m] * (sdelta[so] + sdelta[so + 1]);
    }
    out[idx] = s;
}

extern "C" void kernel_launch(void* const* d_in, const int* in_sizes, int n_in,
                              void* d_out, int out_size, void* d_ws, size_t ws_size,
                              hipStream_t stream) {
    const float* attn   = (const float*)d_in[0];  // [16][100][256] f32
    const float* sdelta = (const float*)d_in[1];  // [16][100][20000][2] f32
    // d_in[2] = traj_len — unused by the reference computation
    const float* embt   = (const float*)d_in[3];  // [20001][256] f32
    const float* vw     = (const float*)d_in[4];  // [1][100] f32
    float* out = (float*)d_out;                   // [16][20000] f32

    const size_t fragShorts = (size_t)PREP_TASKS * 8;                // 524288 u16
    const size_t needed     = fragShorts * sizeof(unsigned short);   // 1 MB

    if (ws_size >= needed) {
        unsigned short* Bf = (unsigned short*)d_ws;
        prep2_kernel<<<PREP_TASKS / 256, 256, 0, stream>>>(attn, vw, Bf);
        main_kernel<<<dim3(NB, NLT), 256, 0, stream>>>(Bf, sdelta, embt, out);
    } else {
        fallback_kernel<<<(NB * LMAX + 255) / 256, 256, 0, stream>>>(attn, sdelta, embt, vw, out);
    }
}

// Round 21
// 74.862 us; speedup vs baseline: 1.3233x; 1.0447x over previous
//
#include <hip/hip_runtime.h>

// Problem constants: B=16, MAX_LEN=100, LOC_MAX=20000, EMB=256, D_DELTA=2
#define NB 16
#define MLEN 100
#define EMBD 256
#define LMAX 20000
#define LTILE 64            // l's per block (lane owns one l)
#define NLT 313             // ceil(20000/64); edge tile masked
#define PREP_TASKS (NB * 4 * 16 * 64)   // 65536: (b,kc4,etg,lane) — layout identical to r16-r20

typedef __attribute__((ext_vector_type(4))) float f32x4;
typedef __attribute__((ext_vector_type(2))) float f32x2;
typedef _Float16 f16x8 __attribute__((ext_vector_type(8)));

__device__ __forceinline__ unsigned short f2h(float x) {
    union { _Float16 f; unsigned short u; } a; a.f = (_Float16)x; return a.u;
}

// ---------------- Kernel 1: pack vwA = vw[m]*attn[b][m][e] into single-f16 MFMA B-fragments ----------------
// frag f = (b*4+kc4)*16 + etg ; lane: e = etg*16 + (lane&15), k = (lane>>4)*8 + j, m = kc4*32 + k
// m >= MLEN -> exact zero  (verified r16-r20)
__global__ __launch_bounds__(256)
void prep2_kernel(const float* __restrict__ attn, const float* __restrict__ vw,
                  unsigned short* __restrict__ Bf) {
    const int gid  = blockIdx.x * 256 + threadIdx.x;   // < 65536
    const int lane = gid & 63;
    const int f    = gid >> 6;
    const int etg  = f & 15;
    const int kcb  = f >> 4;
    const int kc4  = kcb & 3;
    const int b    = kcb >> 2;
    const int e    = etg * 16 + (lane & 15);
    const int m0   = kc4 * 32 + (lane >> 4) * 8;
    unsigned h[8];
    #pragma unroll
    for (int j = 0; j < 8; ++j) {
        const int m = m0 + j;
        float x = 0.f;
        if (m < MLEN) x = vw[m] * attn[((size_t)b * MLEN + m) * EMBD + e];
        h[j] = f2h(x);
    }
    uint4 hi = make_uint4(h[0]|(h[1]<<16), h[2]|(h[3]<<16), h[4]|(h[5]<<16), h[6]|(h[7]<<16));
    reinterpret_cast<uint4*>(Bf)[gid] = hi;
}

// ---------------- Kernel 2: 2-phase (NKC=2, 64-m chunks), everything prefetched at entry ----------------
// Block: (b, 64 l's), 4 waves; wave w owns e-range [w*64,+64). K = 100 m's in 2 chunks of 64.
// ALL 32 sdelta f32x2 loads + ALL 16 B frags issued at kernel entry (max MLP/cover). Per phase:
// writeA(kc) [counted wait on its slot] -> lgkmcnt -> raw s_barrier -> 32 MFMA (2 ks-steps x 4 lt
// x 4 et) vs register B. Only 2 barriers total (buf0 never reused; buf1 protected by phase-1 barrier).
// Wave w stages rows kc*64 + w*16 .. +15 (= kgroups {2w&2|g} of ks=w>>1).
__global__ __launch_bounds__(256, 2)
void main_kernel(const unsigned short* __restrict__ Bf,
                 const float* __restrict__ sdelta, const float* __restrict__ embt,
                 float* __restrict__ out) {
    __shared__ __align__(16) unsigned short AhL[2][4 * 1040];  // 2 x 8320 B: [lt][ks][lane][8]+pads
    __shared__ float red[256];                                 // 1024 B (total 17664 B)

    const int b    = blockIdx.x;
    const int lt0  = blockIdx.y;
    const int l0   = lt0 * LTILE;
    const int w    = threadIdx.x >> 6;
    const int lane = threadIdx.x & 63;
    const int llo  = lane & 15;
    const int lhi  = lane >> 4;

    f32x4 acc[4][4];
    #pragma unroll
    for (int lt = 0; lt < 4; ++lt)
        #pragma unroll
        for (int et = 0; et < 4; ++et)
            acc[lt][et] = (f32x4){0.f, 0.f, 0.f, 0.f};

    // per-lane global source: lane owns ONE l, clamped for edge tile (store masked)
    const int lcl = min(l0 + lane, LMAX - 1);
    const float* sdb = sdelta + (size_t)b * MLEN * (LMAX * 2);

    f32x2 vA[2][16];                     // both chunks resident: 64 VGPR
    auto issueA = [&](int kc) {
        const int q = kc & 1;
        #pragma unroll
        for (int jj = 0; jj < 16; ++jj) {
            const int m  = kc * 64 + w * 16 + jj;
            const int mc = (m < MLEN) ? m : (MLEN - 1);
            vA[q][jj] = *reinterpret_cast<const f32x2*>(sdb + (size_t)mc * (LMAX * 2) + lcl * 2);
        }
    };
    // pair-sum -> f16; lane's 8 j's contiguous -> 2 x ds_write_b128 (one per kgroup)
    auto writeA = [&](int kc) {
        const int q  = kc & 1;
        const int lt = lane >> 4;
        const int ll = lane & 15;
        const int ks = w >> 1;
        #pragma unroll
        for (int g = 0; g < 2; ++g) {
            const int kgrp = (w & 1) * 2 + g;
            unsigned h[8];
            #pragma unroll
            for (int j = 0; j < 8; ++j) {
                const int m = kc * 64 + w * 16 + g * 8 + j;
                const float msk = (m < MLEN) ? 1.f : 0.f;
                const f32x2 v = vA[q][g * 8 + j];
                h[j] = f2h((v[0] + v[1]) * msk);
            }
            const int i0 = lt * 1040 + ks * 520 + (ll | (kgrp << 4)) * 8;
            *reinterpret_cast<uint4*>(&AhL[q][i0]) =
                make_uint4(h[0]|(h[1]<<16), h[2]|(h[3]<<16), h[4]|(h[5]<<16), h[6]|(h[7]<<16));
        }
    };

    // ---- entry: issue EVERYTHING (oldest = chunk 0, so its counted wait drains first) ----
    issueA(0);
    issueA(1);
    f16x8 Bv[2][2][4];                   // [kc][ks][et]: 64 VGPR, register-resident
    #pragma unroll
    for (int kc = 0; kc < 2; ++kc)
        #pragma unroll
        for (int ks = 0; ks < 2; ++ks)
            #pragma unroll
            for (int et = 0; et < 4; ++et) {
                const int kc4 = kc * 2 + ks;
                const size_t bo = (((size_t)(b * 4 + kc4) * 16 + (w * 4 + et)) * 64 + lane) * 8;
                Bv[kc][ks][et] = *reinterpret_cast<const f16x8*>(Bf + bo);
            }

    #pragma unroll
    for (int kc = 0; kc < 2; ++kc) {
        const int q = kc & 1;
        writeA(kc);                              // counted wait on slot q's 16 loads only
        __builtin_amdgcn_sched_barrier(0);
        asm volatile("s_waitcnt lgkmcnt(0)" ::: "memory");
        __builtin_amdgcn_sched_barrier(0);
        __builtin_amdgcn_s_barrier();            // raw barrier: no vmcnt drain
        __builtin_amdgcn_sched_barrier(0);

        #pragma unroll
        for (int lt = 0; lt < 4; ++lt) {
            #pragma unroll
            for (int ks = 0; ks < 2; ++ks) {
                const f16x8 ah = *reinterpret_cast<const f16x8*>(&AhL[q][lt * 1040 + ks * 520 + lane * 8]);
                #pragma unroll
                for (int et = 0; et < 4; ++et)
                    acc[lt][et] = __builtin_amdgcn_mfma_f32_16x16x32_f16(ah, Bv[kc][ks][et], acc[lt][et], 0, 0, 0);
            }
        }
        // no trailing barrier: phase 1 writes buf 1 (disjoint); phase-1's own barrier orders its reads
    }

    // ---------------- epilogue: p[l] = sum_e G[l,e] * E[1+l, e] ----------------
    // C/D layout: col = lane&15 (e), row = (lane>>4)*4 + i (l)  [verified r1-r20]
    float p[4][4];
    #pragma unroll
    for (int lt = 0; lt < 4; ++lt) {
        #pragma unroll
        for (int i = 0; i < 4; ++i) {
            const int l  = l0 + lt * 16 + lhi * 4 + i;
            const int lc = (l < LMAX) ? l : (LMAX - 1);
            const float* Er = embt + (size_t)(1 + lc) * EMBD + w * 64 + llo;
            float s = acc[lt][0][i] * Er[0];
            s += acc[lt][1][i] * Er[16];
            s += acc[lt][2][i] * Er[32];
            s += acc[lt][3][i] * Er[48];
            p[lt][i] = s;
        }
    }
    #pragma unroll
    for (int lt = 0; lt < 4; ++lt)
        #pragma unroll
        for (int i = 0; i < 4; ++i) {
            float x = p[lt][i];
            x += __shfl_xor(x, 1);
            x += __shfl_xor(x, 2);
            x += __shfl_xor(x, 4);
            x += __shfl_xor(x, 8);
            p[lt][i] = x;
        }
    if (llo == 0) {
        #pragma unroll
        for (int lt = 0; lt < 4; ++lt)
            *reinterpret_cast<float4*>(&red[w * 64 + lt * 16 + lhi * 4]) =
                make_float4(p[lt][0], p[lt][1], p[lt][2], p[lt][3]);
    }
    __syncthreads();
    if (threadIdx.x < 64) {
        const int t = threadIdx.x;
        const int l = l0 + t;
        if (l < LMAX) {
            out[(size_t)b * LMAX + l] = red[t] + red[64 + t] + red[128 + t] + red[192 + t];
        }
    }
}

// ---------------- Fallback (ws too small): straightforward f32 compute ----------------
__global__ __launch_bounds__(256)
void fallback_kernel(const float* __restrict__ attn, const float* __restrict__ sdelta,
                     const float* __restrict__ embt, const float* __restrict__ vw,
                     float* __restrict__ out) {
    const int idx = blockIdx.x * 256 + threadIdx.x;
    if (idx >= NB * LMAX) return;
    const int b = idx / LMAX;
    const int l = idx % LMAX;
    float s = 0.f;
    for (int m = 0; m < MLEN; ++m) {
        const float* ar = attn + ((size_t)b * MLEN + m) * EMBD;
        const float* er = embt + (size_t)(l + 1) * EMBD;
        float dot = 0.f;
        for (int e = 0; e < EMBD; ++e) dot += ar[e] * er[e];
        const size_t so = (((size_t)b * MLEN + m) * LMAX + l) * 2;
        s += dot * vw[m] * (sdelta[so] + sdelta[so + 1]);
    }
    out[idx] = s;
}

extern "C" void kernel_launch(void* const* d_in, const int* in_sizes, int n_in,
                              void* d_out, int out_size, void* d_ws, size_t ws_size,
                              hipStream_t stream) {
    const float* attn   = (const float*)d_in[0];  // [16][100][256] f32
    const float* sdelta = (const float*)d_in[1];  // [16][100][20000][2] f32
    // d_in[2] = traj_len — unused by the reference computation
    const float* embt   = (const float*)d_in[3];  // [20001][256] f32
    const float* vw     = (const float*)d_in[4];  // [1][100] f32
    float* out = (float*)d_out;                   // [16][20000] f32

    const size_t fragShorts = (size_t)PREP_TASKS * 8;                // 524288 u16
    const size_t needed     = fragShorts * sizeof(unsigned short);   // 1 MB

    if (ws_size >= needed) {
        unsigned short* Bf = (unsigned short*)d_ws;
        prep2_kernel<<<PREP_TASKS / 256, 256, 0, stream>>>(attn, vw, Bf);
        main_kernel<<<dim3(NB, NLT), 256, 0, stream>>>(Bf, sdelta, embt, out);
    } else {
        fallback_kernel<<<(NB * LMAX + 255) / 256, 256, 0, stream>>>(attn, sdelta, embt, vw, out);
    }
}